// Round 1
// baseline (260.201 us; speedup 1.0000x reference)
//
#include <hip/hip_runtime.h>

// D = H = W = 128, NUM_STEPS = 7 (MONAI DVF2DDF scaling-and-squaring)
#define DD 128
constexpr int NV = DD * DD * DD;          // 2,097,152 voxels
constexpr float INV_SCALE = 1.0f / 128.0f; // 2^-NUM_STEPS

__device__ __forceinline__ void unpack_zyx(int tid, int& z, int& y, int& x) {
    x = tid & (DD - 1);
    y = (tid >> 7) & (DD - 1);
    z = tid >> 14;
}

__device__ __forceinline__ float clamp01(float v) {
    return fminf(fmaxf(v, 0.0f), (float)(DD - 1));
}

// ---------------------------------------------------------------------------
// init: planar dvf [3,D,H,W] -> interleaved A [(D,H,W),3], scaled by 2^-7
// ---------------------------------------------------------------------------
__global__ __launch_bounds__(256)
void init_kernel(const float* __restrict__ dvf, float* __restrict__ A) {
    int tid = blockIdx.x * blockDim.x + threadIdx.x;
    float d0 = dvf[tid] * INV_SCALE;
    float d1 = dvf[tid + NV] * INV_SCALE;
    float d2 = dvf[tid + 2 * NV] * INV_SCALE;
    float* p = A + 3 * tid;
    p[0] = d0; p[1] = d1; p[2] = d2;
}

// ---------------------------------------------------------------------------
// trilinear sample of interleaved 3-channel field at clamped coords
// ---------------------------------------------------------------------------
__device__ __forceinline__ void trilerp3(const float* __restrict__ src,
                                         float cz, float cy, float cx,
                                         float& r0, float& r1, float& r2) {
    float z0f = floorf(cz), y0f = floorf(cy), x0f = floorf(cx);
    float wz = cz - z0f, wy = cy - y0f, wx = cx - x0f;
    int z0 = (int)z0f, y0 = (int)y0f, x0 = (int)x0f;
    int z1 = min(z0 + 1, DD - 1);
    int y1 = min(y0 + 1, DD - 1);
    int x1 = min(x0 + 1, DD - 1);
    float omz = 1.0f - wz, omy = 1.0f - wy, omx = 1.0f - wx;

    int zs0 = z0 << 14, zs1 = z1 << 14;
    int ys0 = y0 << 7,  ys1 = y1 << 7;

    const float* p000 = src + 3 * (zs0 + ys0 + x0);
    const float* p001 = src + 3 * (zs0 + ys0 + x1);
    const float* p010 = src + 3 * (zs0 + ys1 + x0);
    const float* p011 = src + 3 * (zs0 + ys1 + x1);
    const float* p100 = src + 3 * (zs1 + ys0 + x0);
    const float* p101 = src + 3 * (zs1 + ys0 + x1);
    const float* p110 = src + 3 * (zs1 + ys1 + x0);
    const float* p111 = src + 3 * (zs1 + ys1 + x1);

    float w000 = omz * omy * omx, w001 = omz * omy * wx;
    float w010 = omz * wy * omx,  w011 = omz * wy * wx;
    float w100 = wz * omy * omx,  w101 = wz * omy * wx;
    float w110 = wz * wy * omx,   w111 = wz * wy * wx;

    r0 = w000 * p000[0] + w001 * p001[0] + w010 * p010[0] + w011 * p011[0]
       + w100 * p100[0] + w101 * p101[0] + w110 * p110[0] + w111 * p111[0];
    r1 = w000 * p000[1] + w001 * p001[1] + w010 * p010[1] + w011 * p011[1]
       + w100 * p100[1] + w101 * p101[1] + w110 * p110[1] + w111 * p111[1];
    r2 = w000 * p000[2] + w001 * p001[2] + w010 * p010[2] + w011 * p011[2]
       + w100 * p100[2] + w101 * p101[2] + w110 * p110[2] + w111 * p111[2];
}

// ---------------------------------------------------------------------------
// one scaling-and-squaring step: dst = src + warp(src, src)
// src interleaved; dst interleaved (PLANAR_OUT=false) or planar (true)
// ---------------------------------------------------------------------------
template <bool PLANAR_OUT>
__global__ __launch_bounds__(256)
void step_kernel(const float* __restrict__ src, float* __restrict__ dst) {
    int tid = blockIdx.x * blockDim.x + threadIdx.x;
    int z, y, x;
    unpack_zyx(tid, z, y, x);

    const float* s = src + 3 * tid;
    float d0 = s[0], d1 = s[1], d2 = s[2];

    float cz = clamp01((float)z + d0);
    float cy = clamp01((float)y + d1);
    float cx = clamp01((float)x + d2);

    float r0, r1, r2;
    trilerp3(src, cz, cy, cx, r0, r1, r2);

    r0 += d0; r1 += d1; r2 += d2;

    if (PLANAR_OUT) {
        dst[tid]          = r0;
        dst[tid + NV]     = r1;
        dst[tid + 2 * NV] = r2;
    } else {
        float* p = dst + 3 * tid;
        p[0] = r0; p[1] = r1; p[2] = r2;
    }
}

// ---------------------------------------------------------------------------
// final: read planar ddf; bilinear-warp moving_image, nearest-warp
// moving_label, copy dvf through to its output slot
// ---------------------------------------------------------------------------
__global__ __launch_bounds__(256)
void final_kernel(const float* __restrict__ ddf,
                  const float* __restrict__ mimg,
                  const float* __restrict__ mlab,
                  const float* __restrict__ dvf,
                  float* __restrict__ pred_img,
                  float* __restrict__ pred_lab,
                  float* __restrict__ dvf_out) {
    int tid = blockIdx.x * blockDim.x + threadIdx.x;
    int z, y, x;
    unpack_zyx(tid, z, y, x);

    float d0 = ddf[tid];
    float d1 = ddf[tid + NV];
    float d2 = ddf[tid + 2 * NV];

    float cz = clamp01((float)z + d0);
    float cy = clamp01((float)y + d1);
    float cx = clamp01((float)x + d2);

    // --- bilinear warp of moving_image (1 channel, planar) ---
    {
        float z0f = floorf(cz), y0f = floorf(cy), x0f = floorf(cx);
        float wz = cz - z0f, wy = cy - y0f, wx = cx - x0f;
        int z0 = (int)z0f, y0 = (int)y0f, x0 = (int)x0f;
        int z1 = min(z0 + 1, DD - 1);
        int y1 = min(y0 + 1, DD - 1);
        int x1 = min(x0 + 1, DD - 1);
        float omz = 1.0f - wz, omy = 1.0f - wy, omx = 1.0f - wx;
        int zs0 = z0 << 14, zs1 = z1 << 14;
        int ys0 = y0 << 7,  ys1 = y1 << 7;

        float v = omz * omy * omx * mimg[zs0 + ys0 + x0]
                + omz * omy * wx  * mimg[zs0 + ys0 + x1]
                + omz * wy * omx  * mimg[zs0 + ys1 + x0]
                + omz * wy * wx   * mimg[zs0 + ys1 + x1]
                + wz * omy * omx  * mimg[zs1 + ys0 + x0]
                + wz * omy * wx   * mimg[zs1 + ys0 + x1]
                + wz * wy * omx   * mimg[zs1 + ys1 + x0]
                + wz * wy * wx    * mimg[zs1 + ys1 + x1];
        pred_img[tid] = v;
    }

    // --- nearest warp of moving_label (jnp.round = ties-to-even = rintf) ---
    {
        int zi = (int)rintf(cz);
        int yi = (int)rintf(cy);
        int xi = (int)rintf(cx);
        pred_lab[tid] = mlab[(zi << 14) + (yi << 7) + xi];
    }

    // --- dvf pass-through (overwrites scratch buffer A, done last) ---
    dvf_out[tid]          = dvf[tid];
    dvf_out[tid + NV]     = dvf[tid + NV];
    dvf_out[tid + 2 * NV] = dvf[tid + 2 * NV];
}

extern "C" void kernel_launch(void* const* d_in, const int* in_sizes, int n_in,
                              void* d_out, int out_size, void* d_ws, size_t ws_size,
                              hipStream_t stream) {
    const float* dvf  = (const float*)d_in[0];
    const float* mimg = (const float*)d_in[1];
    // d_in[2] = fixed_image: unused by the reference outputs
    const float* mlab = (const float*)d_in[3];

    float* out      = (float*)d_out;
    float* ddf_out  = out;              // slot 0: ddf  [3,D,H,W]
    float* pred_img = out + 3 * NV;     // slot 1
    float* pred_lab = out + 4 * NV;     // slot 2
    float* dvf_out  = out + 5 * NV;     // slot 3: dvf pass-through

    // Ping-pong scratch lives inside d_out (no ws_size assumptions):
    // A = dvf slot (overwritten at the end), B = ddf slot (final step lands here).
    float* A = dvf_out;
    float* B = ddf_out;

    dim3 block(256);
    dim3 grid(NV / 256);  // 8192 blocks

    init_kernel<<<grid, block, 0, stream>>>(dvf, A);
    step_kernel<false><<<grid, block, 0, stream>>>(A, B);  // step 1
    step_kernel<false><<<grid, block, 0, stream>>>(B, A);  // step 2
    step_kernel<false><<<grid, block, 0, stream>>>(A, B);  // step 3
    step_kernel<false><<<grid, block, 0, stream>>>(B, A);  // step 4
    step_kernel<false><<<grid, block, 0, stream>>>(A, B);  // step 5
    step_kernel<false><<<grid, block, 0, stream>>>(B, A);  // step 6
    step_kernel<true ><<<grid, block, 0, stream>>>(A, B);  // step 7 -> planar ddf
    final_kernel<<<grid, block, 0, stream>>>(B, mimg, mlab, dvf,
                                             pred_img, pred_lab, dvf_out);
}